// Round 1
// baseline (360.998 us; speedup 1.0000x reference)
//
#include <hip/hip_runtime.h>
#include <math.h>

#define TLEN   8192
#define BROWS  4096
#define NT     256
#define TILE   2048
#define CHUNK  8          /* TILE / NT */
#define NTILES (TLEN / TILE)
#define GAMMA  0.99f
#define EPSN   1e-9

typedef float f4 __attribute__((ext_vector_type(4)));

// ---------------------------------------------------------------------------
// K1: one row per block, 4 tiles of 2048 processed right-to-left.
// Register-direct loads: thread t owns elements [8t, 8t+8) of the tile via two
// consecutive float4 loads (wave covers a contiguous 2 KB -> cache-line dense).
// Next tile is prefetched into registers at the top of each iteration and
// consumed at the START of the next iteration -> prefetch distance of a full
// tile of compute covers the ~900cy HBM latency (old version waited vmcnt at
// the mid-iteration LDS stash). Cross-wave carry uses per-tile LDS slots
// (indexed by k) so only ONE barrier per tile is needed. No LDS data staging.
// ---------------------------------------------------------------------------
__global__ __launch_bounds__(NT) void er_scan(const float* __restrict__ rew,
                                              const float* __restrict__ don,
                                              float* __restrict__ out,
                                              double* __restrict__ rowSum,
                                              float* __restrict__ rowInv) {
  __shared__ float  wgA[NTILES][4];
  __shared__ float  wgP[NTILES][4];
  __shared__ double red[8];

  const int row  = blockIdx.x;
  const int tid  = threadIdx.x;
  const int lane = tid & 63;
  const int wv   = tid >> 6;
  const size_t rbase = (size_t)row * TLEN;

  const f4* gr = (const f4*)(rew + rbase);
  const f4* gd = (const f4*)(don + rbase);

  // preload last tile
  f4 r0, r1, d0, d1;
  {
    const int f = (NTILES - 1) * (TILE / 4) + 2 * tid;
    r0 = gr[f]; r1 = gr[f + 1];
    d0 = gd[f]; d1 = gd[f + 1];
  }

  double accS = 0.0, accQ = 0.0;
  float  tc = 0.f;   // carry entering the current tile from the right

  for (int k = NTILES - 1; k >= 0; --k) {
    const bool more = (k > 0);
    f4 pr0, pr1, pd0, pd1;
    if (more) {
      const int f = (k - 1) * (TILE / 4) + 2 * tid;
      pr0 = gr[f]; pr1 = gr[f + 1];
      pd0 = gd[f]; pd1 = gd[f + 1];
    }

    // --- unpack own 8-element chunk from registers ---
    float rv[CHUNK], cv[CHUNK];
    rv[0] = r0.x; rv[1] = r0.y; rv[2] = r0.z; rv[3] = r0.w;
    rv[4] = r1.x; rv[5] = r1.y; rv[6] = r1.z; rv[7] = r1.w;
    cv[0] = fmaf(-GAMMA, d0.x, GAMMA);
    cv[1] = fmaf(-GAMMA, d0.y, GAMMA);
    cv[2] = fmaf(-GAMMA, d0.z, GAMMA);
    cv[3] = fmaf(-GAMMA, d0.w, GAMMA);
    cv[4] = fmaf(-GAMMA, d1.x, GAMMA);
    cv[5] = fmaf(-GAMMA, d1.y, GAMMA);
    cv[6] = fmaf(-GAMMA, d1.z, GAMMA);
    cv[7] = fmaf(-GAMMA, d1.w, GAMMA);

    // --- local suffix scan of affine maps T_j(x) = rv + cv*x ---
    float A = 0.f, P = 1.f;
#pragma unroll
    for (int j = CHUNK - 1; j >= 0; --j) {
      A = fmaf(cv[j], A, rv[j]);
      P *= cv[j];
      rv[j] = A;   // A_{[j, chunk end)}
      cv[j] = P;   // P_{[j, chunk end)}
    }

    // --- wave inclusive suffix scan of (A,P) composites ---
    float sA = A, sP = P;
#pragma unroll
    for (int d = 1; d < 64; d <<= 1) {
      const float tA = __shfl_down(sA, d);
      const float tP = __shfl_down(sP, d);
      if (lane + d < 64) { sA = fmaf(sP, tA, sA); sP *= tP; }
    }
    if (lane == 0) { wgA[k][wv] = sA; wgP[k][wv] = sP; }
    __syncthreads();   // only barrier this tile (per-k slots -> no WAR hazard)

    // carry entering this wave = waves (wv,3] composed, applied to tc
    float wc = tc;
#pragma unroll
    for (int j = 3; j >= 1; --j) {
      const float nw = fmaf(wgP[k][j], wc, wgA[k][j]);
      wc = (j > wv) ? nw : wc;
    }
    // next tile's carry = all 4 waves composed, applied to tc
    float tcn = tc;
#pragma unroll
    for (int j = 3; j >= 0; --j) tcn = fmaf(wgP[k][j], tcn, wgA[k][j]);

    // exclusive within wave (lanes above), then apply wave carry
    float eA = __shfl_down(sA, 1);
    float eP = __shfl_down(sP, 1);
    if (lane == 63) { eA = 0.f; eP = 1.f; }
    const float carry = fmaf(eP, wc, eA);

    // --- fixup, store, stats ---
    float fsum = 0.f, fsq = 0.f;
    float o[CHUNK];
#pragma unroll
    for (int j = 0; j < CHUNK; ++j) {
      const float r = fmaf(cv[j], carry, rv[j]);
      o[j] = r;
      fsum += r;
      fsq  = fmaf(r, r, fsq);
    }
    f4* go = (f4*)(out + rbase + (size_t)k * TILE + (size_t)tid * CHUNK);
    f4 o0; o0.x = o[0]; o0.y = o[1]; o0.z = o[2]; o0.w = o[3];
    f4 o1; o1.x = o[4]; o1.y = o[5]; o1.z = o[6]; o1.w = o[7];
    go[0] = o0;
    go[1] = o1;
    accS += (double)fsum;
    accQ += (double)fsq;
    tc = tcn;

    if (more) { r0 = pr0; r1 = pr1; d0 = pd0; d1 = pd1; }
  }

  // --- block reduction (double) for row stats ---
  double ds = accS, dq = accQ;
#pragma unroll
  for (int d = 32; d >= 1; d >>= 1) {
    ds += __shfl_down(ds, d);
    dq += __shfl_down(dq, d);
  }
  if (lane == 0) { red[wv] = ds; red[4 + wv] = dq; }
  __syncthreads();
  if (tid == 0) {
    const double s = red[0] + red[1] + red[2] + red[3];
    const double q = red[4] + red[5] + red[6] + red[7];
    rowSum[row] = s;
    double var = (q - s * s / (double)TLEN) / (double)(TLEN - 1);
    if (var < 0.0) var = 0.0;
    rowInv[row] = (float)(1.0 / (sqrt(var) + EPSN));
  }
}

// ---------------------------------------------------------------------------
// K2: reduce 4096 per-row sums -> global mean (single block)
// ---------------------------------------------------------------------------
__global__ __launch_bounds__(256) void er_mean(const double* __restrict__ rowSum,
                                               float* __restrict__ meanPtr) {
  const int tid = threadIdx.x;
  double s = 0.0;
  for (int i = tid; i < BROWS; i += 256) s += rowSum[i];
#pragma unroll
  for (int d = 32; d >= 1; d >>= 1) s += __shfl_down(s, d);
  __shared__ double red[4];
  const int lane = tid & 63, wv = tid >> 6;
  if (lane == 0) red[wv] = s;
  __syncthreads();
  if (tid == 0) {
    const double t = red[0] + red[1] + red[2] + red[3];
    *meanPtr = (float)(t / ((double)BROWS * (double)TLEN));
  }
}

// ---------------------------------------------------------------------------
// K3: out = (out - mean) * invstd[row]; grid-stride over the flat array
// (G11: cap grid at 2048 blocks), float4, nontemporal final stores so the
// output does not evict the inputs from L3 (next iteration re-reads them).
// ---------------------------------------------------------------------------
#define K3_BLOCKS 2048
__global__ __launch_bounds__(256) void er_norm(float* __restrict__ out,
                                               const float* __restrict__ rowInv,
                                               const float* __restrict__ meanPtr) {
  const float mean = *meanPtr;
  const unsigned total4 = (unsigned)BROWS * (TLEN / 4);
  const unsigned stride = K3_BLOCKS * 256;
  f4* o4 = (f4*)out;
  for (unsigned i = blockIdx.x * 256 + threadIdx.x; i < total4; i += stride) {
    const int row = (int)(i >> 11);          // TLEN/4 = 2048 float4 per row
    const float inv = rowInv[row];
    f4 v = o4[i];
    v.x = (v.x - mean) * inv;
    v.y = (v.y - mean) * inv;
    v.z = (v.z - mean) * inv;
    v.w = (v.w - mean) * inv;
    __builtin_nontemporal_store(v, o4 + i);
  }
}

extern "C" void kernel_launch(void* const* d_in, const int* in_sizes, int n_in,
                              void* d_out, int out_size, void* d_ws, size_t ws_size,
                              hipStream_t stream) {
  const float* rew = (const float*)d_in[0];
  const float* don = (const float*)d_in[1];
  float* out = (float*)d_out;

  double* rowSum  = (double*)d_ws;
  float*  rowInv  = (float*)((char*)d_ws + BROWS * 8);
  float*  meanPtr = (float*)((char*)d_ws + BROWS * 8 + BROWS * 4);

  er_scan<<<BROWS, NT, 0, stream>>>(rew, don, out, rowSum, rowInv);
  er_mean<<<1, 256, 0, stream>>>(rowSum, meanPtr);
  er_norm<<<K3_BLOCKS, 256, 0, stream>>>(out, rowInv, meanPtr);
}